// Round 1
// baseline (9444.726 us; speedup 1.0000x reference)
//
#include <hip/hip_runtime.h>
#include <math.h>

#define NVOX 60000

// ---------------------------------------------------------------- pos embed
__global__ __launch_bounds__(256) void pos_kernel(const float* __restrict__ ciw,
                                                  float* __restrict__ pos) {
    int idx = blockIdx.x * 256 + threadIdx.x;
    if (idx >= NVOX * 128) return;
    int n = idx >> 7, d = idx & 127;
    int c = d >> 6, t = (d & 63) >> 1;
    float xy = ciw[n * 2 + c] - 6.0f;                       // WIN/2
    float inv = exp2f((float)t * (13.287712379549449f / 32.0f)); // 10000^(t/32)
    float e = xy / inv;
    pos[idx] = (d & 1) ? cosf(e) : sinf(e);
}

// ------------------------------------------------- generic GEMM C = A*W^T + b
// A[M,KTOT] row-major, W[N,KTOT] row-major, C[M,ldc]; optional A += Aadd for
// column-blocks < add_nblk (qk_in = feat + pos); optional exact-GELU epilogue.
template<int KTOT, bool GELU>
__global__ __launch_bounds__(256) void gemm_atb(
    const float* __restrict__ A, const float* __restrict__ Aadd, int add_nblk,
    const float* __restrict__ W, const float* __restrict__ bias,
    float* __restrict__ C, int M, int ldc)
{
    __shared__ float As[64][132];
    __shared__ float Ws[64][132];
    const int tid = threadIdx.x;
    const int tx = tid & 15, ty = tid >> 4;
    const int m0 = blockIdx.x * 64;
    const int n0 = blockIdx.y * 64;
    const bool addp = (Aadd != nullptr) && ((int)blockIdx.y < add_nblk);
    float acc[4][4] = {};
    for (int k0 = 0; k0 < KTOT; k0 += 128) {
        #pragma unroll
        for (int p = 0; p < 8; ++p) {
            int idx = tid + p * 256;
            int r = idx >> 5;
            int cc = (idx & 31) << 2;
            int m = m0 + r;
            float4 v = make_float4(0.f, 0.f, 0.f, 0.f);
            if (m < M) {
                v = *reinterpret_cast<const float4*>(A + (size_t)m * KTOT + k0 + cc);
                if (addp) {
                    float4 u = *reinterpret_cast<const float4*>(Aadd + (size_t)m * 128 + cc);
                    v.x += u.x; v.y += u.y; v.z += u.z; v.w += u.w;
                }
            }
            *reinterpret_cast<float4*>(&As[r][cc]) = v;
            *reinterpret_cast<float4*>(&Ws[r][cc]) =
                *reinterpret_cast<const float4*>(W + (size_t)(n0 + r) * KTOT + k0 + cc);
        }
        __syncthreads();
        #pragma unroll 8
        for (int kc = 0; kc < 32; ++kc) {
            float4 a[4], w[4];
            #pragma unroll
            for (int i = 0; i < 4; ++i)
                a[i] = *reinterpret_cast<const float4*>(&As[ty + 16 * i][kc * 4]);
            #pragma unroll
            for (int j = 0; j < 4; ++j)
                w[j] = *reinterpret_cast<const float4*>(&Ws[tx + 16 * j][kc * 4]);
            #pragma unroll
            for (int i = 0; i < 4; ++i)
                #pragma unroll
                for (int j = 0; j < 4; ++j)
                    acc[i][j] += a[i].x * w[j].x + a[i].y * w[j].y
                               + a[i].z * w[j].z + a[i].w * w[j].w;
        }
        __syncthreads();
    }
    #pragma unroll
    for (int i = 0; i < 4; ++i) {
        int m = m0 + ty + 16 * i;
        if (m >= M) continue;
        #pragma unroll
        for (int j = 0; j < 4; ++j) {
            int n = n0 + tx + 16 * j;
            float v = acc[i][j] + bias[n];
            if (GELU) v = 0.5f * v * (1.0f + erff(v * 0.7071067811865475f));
            C[(size_t)m * ldc + n] = v;
        }
    }
}

// ------------------------------------------------------- windowed attention
// One block = one window (x head-group). Window w of a level is the contiguous
// token slice v[w*CAPT : w*CAPT+T].  Online softmax, 16-dim heads in registers.
template<int CAPT, int HG>
__global__ __launch_bounds__(256) void attn_kernel(
    const float* __restrict__ qkv, const int* __restrict__ vlist, int nvox,
    float* __restrict__ oout)
{
    __shared__ float Ks[CAPT][HG * 16];
    __shared__ float Vs[CAPT][HG * 16];
    __shared__ int vl[CAPT];
    const int w = blockIdx.x;
    const int hb = blockIdx.y * HG;
    const int tid = threadIdx.x;
    const int T = min(CAPT, nvox - w * CAPT);
    if (tid < T) vl[tid] = vlist[w * CAPT + tid];
    constexpr int R4 = HG * 4;   // float4 per staged row
    for (int idx = tid; idx < T * R4; idx += 256) {
        int t = idx / R4, c4 = (idx % R4) * 4;
        int vox = vlist[w * CAPT + t];
        const float* base = qkv + (size_t)vox * 384 + hb * 16 + c4;
        *reinterpret_cast<float4*>(&Ks[t][c4]) = *reinterpret_cast<const float4*>(base + 128);
        *reinterpret_cast<float4*>(&Vs[t][c4]) = *reinterpret_cast<const float4*>(base + 256);
    }
    __syncthreads();
    const int ITEMS = T * HG;
    for (int item = tid; item < ITEMS; item += 256) {
        int h = item & (HG - 1);
        int q = item / HG;
        int vq = vl[q];
        const float4* qp = reinterpret_cast<const float4*>(qkv + (size_t)vq * 384 + (hb + h) * 16);
        float4 q0 = qp[0], q1 = qp[1], q2 = qp[2], q3 = qp[3];
        float mx = -INFINITY, l = 0.f;
        float4 o0 = make_float4(0,0,0,0), o1 = o0, o2 = o0, o3 = o0;
        for (int t = 0; t < T; ++t) {
            const float4* kr = reinterpret_cast<const float4*>(&Ks[t][h * 16]);
            float4 k0 = kr[0], k1 = kr[1], k2 = kr[2], k3 = kr[3];
            float s = q0.x*k0.x + q0.y*k0.y + q0.z*k0.z + q0.w*k0.w
                    + q1.x*k1.x + q1.y*k1.y + q1.z*k1.z + q1.w*k1.w
                    + q2.x*k2.x + q2.y*k2.y + q2.z*k2.z + q2.w*k2.w
                    + q3.x*k3.x + q3.y*k3.y + q3.z*k3.z + q3.w*k3.w;
            s *= 0.25f;                       // 1/sqrt(16)
            float mo = mx;
            mx = fmaxf(mx, s);
            float cc = __expf(mo - mx);
            float p  = __expf(s - mx);
            l = l * cc + p;
            const float4* vr = reinterpret_cast<const float4*>(&Vs[t][h * 16]);
            float4 v0 = vr[0], v1 = vr[1], v2 = vr[2], v3 = vr[3];
            o0.x = o0.x*cc + p*v0.x; o0.y = o0.y*cc + p*v0.y; o0.z = o0.z*cc + p*v0.z; o0.w = o0.w*cc + p*v0.w;
            o1.x = o1.x*cc + p*v1.x; o1.y = o1.y*cc + p*v1.y; o1.z = o1.z*cc + p*v1.z; o1.w = o1.w*cc + p*v1.w;
            o2.x = o2.x*cc + p*v2.x; o2.y = o2.y*cc + p*v2.y; o2.z = o2.z*cc + p*v2.z; o2.w = o2.w*cc + p*v2.w;
            o3.x = o3.x*cc + p*v3.x; o3.y = o3.y*cc + p*v3.y; o3.z = o3.z*cc + p*v3.z; o3.w = o3.w*cc + p*v3.w;
        }
        float rl = 1.0f / l;
        float4* op = reinterpret_cast<float4*>(oout + (size_t)vq * 128 + (hb + h) * 16);
        op[0] = make_float4(o0.x*rl, o0.y*rl, o0.z*rl, o0.w*rl);
        op[1] = make_float4(o1.x*rl, o1.y*rl, o1.z*rl, o1.w*rl);
        op[2] = make_float4(o2.x*rl, o2.y*rl, o2.z*rl, o2.w*rl);
        op[3] = make_float4(o3.x*rl, o3.y*rl, o3.z*rl, o3.w*rl);
    }
}

// ------------------------------------------------ residual + LayerNorm (D=128)
__global__ __launch_bounds__(256) void ln_res(float* __restrict__ feat,
    const float* __restrict__ delta, const float* __restrict__ g,
    const float* __restrict__ b)
{
    int row = blockIdx.x * 4 + (threadIdx.x >> 6);
    int lane = threadIdx.x & 63;
    const size_t base = (size_t)row * 128 + lane * 2;
    float2 f  = *reinterpret_cast<const float2*>(feat + base);
    float2 dd = *reinterpret_cast<const float2*>(delta + base);
    float x0 = f.x + dd.x, x1 = f.y + dd.y;
    float s = x0 + x1, ss = x0 * x0 + x1 * x1;
    #pragma unroll
    for (int off = 32; off; off >>= 1) { s += __shfl_xor(s, off); ss += __shfl_xor(ss, off); }
    float mu = s * 0.0078125f;
    float var = fmaxf(ss * 0.0078125f - mu * mu, 0.f);
    float inv = rsqrtf(var + 1e-5f);
    float2 gg = *reinterpret_cast<const float2*>(g + lane * 2);
    float2 bb = *reinterpret_cast<const float2*>(b + lane * 2);
    float2 r;
    r.x = (x0 - mu) * inv * gg.x + bb.x;
    r.y = (x1 - mu) * inv * gg.y + bb.y;
    *reinterpret_cast<float2*>(feat + base) = r;
}

// ------------------------------------------------------------- BEV scatter
__global__ __launch_bounds__(256) void scatter_kernel(const float* __restrict__ feat,
    const int* __restrict__ coors, float* __restrict__ canvas)
{
    int idx = blockIdx.x * 256 + threadIdx.x;
    if (idx >= NVOX * 32) return;
    int n = idx >> 5, c4 = (idx & 31) << 2;
    int b = coors[n * 4], y = coors[n * 4 + 2], x = coors[n * 4 + 3];
    size_t p = (((size_t)b * 400 + y) * 400 + x) * 128 + c4;
    *reinterpret_cast<float4*>(canvas + p) =
        *reinterpret_cast<const float4*>(feat + (size_t)n * 128 + c4);
}

// ------------------------------------- conv weight re-layout [i][ky*3+kx][co][ci]
__global__ __launch_bounds__(256) void wtrans_kernel(const float* __restrict__ cw,
                                                     float* __restrict__ wbuf)
{
    int idx = blockIdx.x * 256 + threadIdx.x;
    if (idx >= 2 * 9 * 128 * 128) return;
    int ci = idx & 127;
    int co = (idx >> 7) & 127;
    int kk = (idx >> 14) % 9;
    int i  = idx / (9 * 16384);
    wbuf[idx] = cw[(((size_t)i * 128 + co) * 128 + ci) * 9 + kk];
}

// --------------------------- 3x3 dilated(2) conv + BN(eval) + ReLU, implicit GEMM
// in: NHWC (2,400,400,128).  NCHW_OUT picks output layout (conv2 emits NCHW).
template<bool NCHW_OUT>
__global__ __launch_bounds__(256) void conv3x3(
    const float* __restrict__ in, const float* __restrict__ wbuf,
    const float* __restrict__ g, const float* __restrict__ bsh,
    const float* __restrict__ bm, const float* __restrict__ bv,
    float* __restrict__ out)
{
    __shared__ float As[68][132];
    __shared__ float Ws[64][132];
    const int tid = threadIdx.x;
    const int y = blockIdx.y;
    const int x0 = blockIdx.x * 64;
    const int b = blockIdx.z >> 1, cb = blockIdx.z & 1;
    int tp, tc;   // pixel lane / channel lane (swapped so stores coalesce)
    if (NCHW_OUT) { tp = tid & 15; tc = tid >> 4; } else { tc = tid & 15; tp = tid >> 4; }
    float acc[4][4] = {};
    for (int ky = 0; ky < 3; ++ky) {
        int yy = y + 2 * ky - 2;
        __syncthreads();
        for (int p = 0; p < 9; ++p) {
            int idx = tid + p * 256;
            if (idx < 68 * 32) {
                int c = idx >> 5, q4 = (idx & 31) << 2;
                int xx = x0 - 2 + c;
                float4 v = make_float4(0,0,0,0);
                if (yy >= 0 && yy < 400 && xx >= 0 && xx < 400)
                    v = *reinterpret_cast<const float4*>(in + (((size_t)b * 400 + yy) * 400 + xx) * 128 + q4);
                *reinterpret_cast<float4*>(&As[c][q4]) = v;
            }
        }
        for (int kx = 0; kx < 3; ++kx) {
            __syncthreads();
            const float* wsrc = wbuf + ((size_t)(ky * 3 + kx) * 128 + cb * 64) * 128;
            #pragma unroll
            for (int p = 0; p < 8; ++p) {
                int idx = tid + p * 256;
                int r = idx >> 5, c4 = (idx & 31) << 2;
                *reinterpret_cast<float4*>(&Ws[r][c4]) =
                    *reinterpret_cast<const float4*>(wsrc + r * 128 + c4);
            }
            __syncthreads();
            #pragma unroll 8
            for (int kc = 0; kc < 32; ++kc) {
                float4 a[4], w[4];
                #pragma unroll
                for (int i = 0; i < 4; ++i)
                    a[i] = *reinterpret_cast<const float4*>(&As[tp + 16 * i + 2 * kx][kc * 4]);
                #pragma unroll
                for (int j = 0; j < 4; ++j)
                    w[j] = *reinterpret_cast<const float4*>(&Ws[tc + 16 * j][kc * 4]);
                #pragma unroll
                for (int i = 0; i < 4; ++i)
                    #pragma unroll
                    for (int j = 0; j < 4; ++j)
                        acc[i][j] += a[i].x*w[j].x + a[i].y*w[j].y
                                   + a[i].z*w[j].z + a[i].w*w[j].w;
            }
        }
    }
    #pragma unroll
    for (int j = 0; j < 4; ++j) {
        int co = cb * 64 + tc + 16 * j;
        float scale = rsqrtf(bv[co] + 1e-3f) * g[co];
        float shift = bsh[co] - bm[co] * scale;
        #pragma unroll
        for (int i = 0; i < 4; ++i) {
            int x = x0 + tp + 16 * i;
            if (x >= 400) continue;
            float v = fmaxf(acc[i][j] * scale + shift, 0.f);
            if (NCHW_OUT)
                out[(((size_t)b * 128 + co) * 400 + y) * 400 + x] = v;
            else
                out[(((size_t)b * 400 + y) * 400 + x) * 128 + co] = v;
        }
    }
}

// ---------------------------------------------------------------- launcher
extern "C" void kernel_launch(void* const* d_in, const int* in_sizes, int n_in,
                              void* d_out, int out_size, void* d_ws, size_t ws_size,
                              hipStream_t stream) {
    const float* voxel_feat = (const float*)d_in[0];
    const int*   coors      = (const int*)d_in[1];
    const float* ciw0       = (const float*)d_in[2];
    const float* ciw1       = (const float*)d_in[3];
    const int* vx[2][2] = {{(const int*)d_in[4], (const int*)d_in[6]},
                           {(const int*)d_in[8], (const int*)d_in[10]}};
    const float* ipw = (const float*)d_in[12];
    const float* ipb = (const float*)d_in[13];
    const float* ow  = (const float*)d_in[14];
    const float* obp = (const float*)d_in[15];
    const float* l1w = (const float*)d_in[16];
    const float* l1b = (const float*)d_in[17];
    const float* l2w = (const float*)d_in[18];
    const float* l2b = (const float*)d_in[19];
    const float* g1  = (const float*)d_in[20];
    const float* b1  = (const float*)d_in[21];
    const float* g2  = (const float*)d_in[22];
    const float* b2  = (const float*)d_in[23];
    const float* cw  = (const float*)d_in[24];
    const float* bng = (const float*)d_in[25];
    const float* bnb = (const float*)d_in[26];
    const float* bnm = (const float*)d_in[27];
    const float* bnv = (const float*)d_in[28];

    float* F      = (float*)d_ws;
    float* feat   = F;                     // 7.68M floats
    float* attnb  = F + 7680000;           // 7.68M  (attn_out / FFN tmp)
    float* pos0   = F + 15360000;          // 7.68M
    float* pos1   = F + 23040000;          // 7.68M
    float* obuf   = F + 30720000;          // 7.68M  (attention output)
    float* hbuf   = F + 38400000;          // 15.36M (FFN hidden)
    float* canvas = F + 15360000;          // 40.96M NHWC canvas (overlaps pos..h after layers)
    float* wbuf   = F + 56320000;          // 294912 conv weights re-layout
    float* qkv    = (float*)d_out;         // 23.04M <= out_size, scratch during layers

    hipMemcpyAsync(feat, voxel_feat, (size_t)7680000 * 4, hipMemcpyDeviceToDevice, stream);
    pos_kernel<<<30000, 256, 0, stream>>>(ciw0, pos0);
    pos_kernel<<<30000, 256, 0, stream>>>(ciw1, pos1);
    wtrans_kernel<<<(2 * 9 * 16384 + 255) / 256, 256, 0, stream>>>(cw, wbuf);

    for (int li = 0; li < 12; ++li) {
        int s = li & 1;
        const float* pos = s ? pos1 : pos0;
        gemm_atb<128, false><<<dim3(938, 6), 256, 0, stream>>>(
            feat, pos, 4, ipw + (size_t)li * 384 * 128, ipb + li * 384, qkv, NVOX, 384);
        attn_kernel<25, 8><<<dim3(960, 1), 256, 0, stream>>>(qkv, vx[s][0], 24000, obuf);
        attn_kernel<100, 4><<<dim3(360, 2), 256, 0, stream>>>(qkv, vx[s][1], 36000, obuf);
        gemm_atb<128, false><<<dim3(938, 2), 256, 0, stream>>>(
            obuf, nullptr, 0, ow + (size_t)li * 128 * 128, obp + li * 128, attnb, NVOX, 128);
        ln_res<<<15000, 256, 0, stream>>>(feat, attnb, g1 + li * 128, b1 + li * 128);
        gemm_atb<128, true><<<dim3(938, 4), 256, 0, stream>>>(
            feat, nullptr, 0, l1w + (size_t)li * 256 * 128, l1b + li * 256, hbuf, NVOX, 256);
        gemm_atb<256, false><<<dim3(938, 2), 256, 0, stream>>>(
            hbuf, nullptr, 0, l2w + (size_t)li * 128 * 256, l2b + li * 128, attnb, NVOX, 128);
        ln_res<<<15000, 256, 0, stream>>>(feat, attnb, g2 + li * 128, b2 + li * 128);
    }

    // BEV: zero canvas, scatter, conv1 (NHWC->NHWC into d_out), conv2 (->NCHW canvas), copy out
    hipMemsetAsync(canvas, 0, (size_t)40960000 * 4, stream);
    scatter_kernel<<<(NVOX * 32 + 255) / 256, 256, 0, stream>>>(feat, coors, canvas);
    conv3x3<false><<<dim3(7, 400, 4), 256, 0, stream>>>(
        canvas, wbuf, bng, bnb, bnm, bnv, (float*)d_out);
    conv3x3<true><<<dim3(7, 400, 4), 256, 0, stream>>>(
        (float*)d_out, wbuf + 9 * 16384, bng + 128, bnb + 128, bnm + 128, bnv + 128, canvas);
    hipMemcpyAsync(d_out, canvas, (size_t)40960000 * 4, hipMemcpyDeviceToDevice, stream);
}

// Round 2
// 3994.146 us; speedup vs baseline: 2.3646x; 2.3646x over previous
//
#include <hip/hip_runtime.h>
#include <math.h>

#define NVOX 60000

typedef __attribute__((ext_vector_type(8))) short short8v;   // 8 bf16
typedef __attribute__((ext_vector_type(4))) float f32x4;

static __device__ __forceinline__ unsigned short f2bf(float f) {
    unsigned u = __float_as_uint(f);
    unsigned r = (u + 0x7fffu + ((u >> 16) & 1u)) >> 16;
    return (unsigned short)r;
}

// ---------------------------------------------------------------- pos embed
__global__ __launch_bounds__(256) void pos_kernel(const float* __restrict__ ciw,
                                                  float* __restrict__ pos) {
    int idx = blockIdx.x * 256 + threadIdx.x;
    if (idx >= NVOX * 128) return;
    int n = idx >> 7, d = idx & 127;
    int c = d >> 6, t = (d & 63) >> 1;
    float xy = ciw[n * 2 + c] - 6.0f;
    float inv = exp2f((float)t * (13.287712379549449f / 32.0f)); // 10000^(t/32)
    float e = xy / inv;
    pos[idx] = (d & 1) ? cosf(e) : sinf(e);
}

// ------------------------------------------------------- fp32 -> bf16 convert
__global__ __launch_bounds__(256) void cvt_bf16(const float* __restrict__ in,
                                                unsigned short* __restrict__ out, int n) {
    int idx = blockIdx.x * 256 + threadIdx.x;
    if (idx < n) out[idx] = f2bf(in[idx]);
}

// ----------------------------------------- MFMA GEMM: C = A(f32->bf16)*W^T + b
// A[M,KTOT] f32 row-major, W[N,KTOT] bf16 row-major, C[M,ldc] f32.
// Optional A += Aadd (K=128) for blockIdx.y < add_nblk; optional exact GELU.
template<int KTOT, bool GELU>
__global__ __launch_bounds__(256) void gemm_mfma(
    const float* __restrict__ A, const float* __restrict__ Aadd, int add_nblk,
    const unsigned short* __restrict__ W, const float* __restrict__ bias,
    float* __restrict__ C, int M, int ldc)
{
    __shared__ unsigned short As[128 * 64];
    __shared__ unsigned short Ws[128 * 64];
    const int tid = threadIdx.x;
    const int lane = tid & 63, wave = tid >> 6;
    const int wr = wave >> 1, wc = wave & 1;
    const int llo = lane & 15, lhi = lane >> 4;
    const int m0 = blockIdx.x * 128;
    const int n0 = blockIdx.y * 128;
    const bool addp = (Aadd != nullptr) && ((int)blockIdx.y < add_nblk);
    f32x4 acc[4][4] = {};

    for (int k0 = 0; k0 < KTOT; k0 += 64) {
        // ---- stage A (convert f32->bf16) and W, both XOR-swizzled
        #pragma unroll
        for (int p = 0; p < 4; ++p) {
            int c = tid + p * 256;          // 16B chunk id, 1024 total
            int r = c >> 3, c16 = c & 7;
            int addr = r * 128 + ((c16 * 16) ^ ((r & 7) << 4));
            int m = m0 + r;
            float vv[8];
            if (m < M) {
                const float* src = A + (size_t)m * KTOT + k0 + c16 * 8;
                float4 u0 = *reinterpret_cast<const float4*>(src);
                float4 u1 = *reinterpret_cast<const float4*>(src + 4);
                vv[0]=u0.x; vv[1]=u0.y; vv[2]=u0.z; vv[3]=u0.w;
                vv[4]=u1.x; vv[5]=u1.y; vv[6]=u1.z; vv[7]=u1.w;
                if (addp) {
                    const float* ps = Aadd + (size_t)m * 128 + k0 + c16 * 8;
                    float4 p0 = *reinterpret_cast<const float4*>(ps);
                    float4 p1 = *reinterpret_cast<const float4*>(ps + 4);
                    vv[0]+=p0.x; vv[1]+=p0.y; vv[2]+=p0.z; vv[3]+=p0.w;
                    vv[4]+=p1.x; vv[5]+=p1.y; vv[6]+=p1.z; vv[7]+=p1.w;
                }
            } else {
                #pragma unroll
                for (int q = 0; q < 8; ++q) vv[q] = 0.f;
            }
            short8v av;
            #pragma unroll
            for (int q = 0; q < 8; ++q) av[q] = (short)f2bf(vv[q]);
            *reinterpret_cast<short8v*>((char*)As + addr) = av;
            *reinterpret_cast<short8v*>((char*)Ws + addr) =
                *reinterpret_cast<const short8v*>(W + (size_t)(n0 + r) * KTOT + k0 + c16 * 8);
        }
        __syncthreads();
        #pragma unroll
        for (int kk = 0; kk < 2; ++kk) {
            int kb = kk * 64 + lhi * 16;
            short8v af[4], bf[4];
            #pragma unroll
            for (int i = 0; i < 4; ++i) {
                int r = wr * 64 + i * 16 + llo;
                af[i] = *reinterpret_cast<const short8v*>((const char*)As + r * 128 + (kb ^ ((r & 7) << 4)));
                int cc = wc * 64 + i * 16 + llo;
                bf[i] = *reinterpret_cast<const short8v*>((const char*)Ws + cc * 128 + (kb ^ ((cc & 7) << 4)));
            }
            #pragma unroll
            for (int i = 0; i < 4; ++i)
                #pragma unroll
                for (int j = 0; j < 4; ++j)
                    acc[i][j] = __builtin_amdgcn_mfma_f32_16x16x32_bf16(af[i], bf[j], acc[i][j], 0, 0, 0);
        }
        __syncthreads();
    }
    // ---- epilogue: bias (+GELU), fp32 store
    #pragma unroll
    for (int j = 0; j < 4; ++j) {
        int n = n0 + wc * 64 + j * 16 + llo;
        float bn = bias[n];
        #pragma unroll
        for (int i = 0; i < 4; ++i) {
            #pragma unroll
            for (int rg = 0; rg < 4; ++rg) {
                int m = m0 + wr * 64 + i * 16 + lhi * 4 + rg;
                if (m < M) {
                    float v = acc[i][j][rg] + bn;
                    if (GELU) v = 0.5f * v * (1.0f + erff(v * 0.7071067811865475f));
                    C[(size_t)m * ldc + n] = v;
                }
            }
        }
    }
}

// ------------------------------------------------------- windowed attention
template<int CAPT, int HG>
__global__ __launch_bounds__(256) void attn_kernel(
    const float* __restrict__ qkv, const int* __restrict__ vlist, int nvox,
    float* __restrict__ oout)
{
    __shared__ float Ks[CAPT][HG * 16];
    __shared__ float Vs[CAPT][HG * 16];
    __shared__ int vl[CAPT];
    const int w = blockIdx.x;
    const int hb = blockIdx.y * HG;
    const int tid = threadIdx.x;
    const int T = min(CAPT, nvox - w * CAPT);
    if (tid < T) vl[tid] = vlist[w * CAPT + tid];
    constexpr int R4 = HG * 4;
    for (int idx = tid; idx < T * R4; idx += 256) {
        int t = idx / R4, c4 = (idx % R4) * 4;
        int vox = vlist[w * CAPT + t];
        const float* base = qkv + (size_t)vox * 384 + hb * 16 + c4;
        *reinterpret_cast<float4*>(&Ks[t][c4]) = *reinterpret_cast<const float4*>(base + 128);
        *reinterpret_cast<float4*>(&Vs[t][c4]) = *reinterpret_cast<const float4*>(base + 256);
    }
    __syncthreads();
    const int ITEMS = T * HG;
    for (int item = tid; item < ITEMS; item += 256) {
        int h = item & (HG - 1);
        int q = item / HG;
        int vq = vl[q];
        const float4* qp = reinterpret_cast<const float4*>(qkv + (size_t)vq * 384 + (hb + h) * 16);
        float4 q0 = qp[0], q1 = qp[1], q2 = qp[2], q3 = qp[3];
        float mx = -INFINITY, l = 0.f;
        float4 o0 = make_float4(0,0,0,0), o1 = o0, o2 = o0, o3 = o0;
        for (int t = 0; t < T; ++t) {
            const float4* kr = reinterpret_cast<const float4*>(&Ks[t][h * 16]);
            float4 k0 = kr[0], k1 = kr[1], k2 = kr[2], k3 = kr[3];
            float s = q0.x*k0.x + q0.y*k0.y + q0.z*k0.z + q0.w*k0.w
                    + q1.x*k1.x + q1.y*k1.y + q1.z*k1.z + q1.w*k1.w
                    + q2.x*k2.x + q2.y*k2.y + q2.z*k2.z + q2.w*k2.w
                    + q3.x*k3.x + q3.y*k3.y + q3.z*k3.z + q3.w*k3.w;
            s *= 0.25f;
            float mo = mx;
            mx = fmaxf(mx, s);
            float cc = __expf(mo - mx);
            float p  = __expf(s - mx);
            l = l * cc + p;
            const float4* vr = reinterpret_cast<const float4*>(&Vs[t][h * 16]);
            float4 v0 = vr[0], v1 = vr[1], v2 = vr[2], v3 = vr[3];
            o0.x = o0.x*cc + p*v0.x; o0.y = o0.y*cc + p*v0.y; o0.z = o0.z*cc + p*v0.z; o0.w = o0.w*cc + p*v0.w;
            o1.x = o1.x*cc + p*v1.x; o1.y = o1.y*cc + p*v1.y; o1.z = o1.z*cc + p*v1.z; o1.w = o1.w*cc + p*v1.w;
            o2.x = o2.x*cc + p*v2.x; o2.y = o2.y*cc + p*v2.y; o2.z = o2.z*cc + p*v2.z; o2.w = o2.w*cc + p*v2.w;
            o3.x = o3.x*cc + p*v3.x; o3.y = o3.y*cc + p*v3.y; o3.z = o3.z*cc + p*v3.z; o3.w = o3.w*cc + p*v3.w;
        }
        float rl = 1.0f / l;
        float4* op = reinterpret_cast<float4*>(oout + (size_t)vq * 128 + (hb + h) * 16);
        op[0] = make_float4(o0.x*rl, o0.y*rl, o0.z*rl, o0.w*rl);
        op[1] = make_float4(o1.x*rl, o1.y*rl, o1.z*rl, o1.w*rl);
        op[2] = make_float4(o2.x*rl, o2.y*rl, o2.z*rl, o2.w*rl);
        op[3] = make_float4(o3.x*rl, o3.y*rl, o3.z*rl, o3.w*rl);
    }
}

// ------------------------------------------------ residual + LayerNorm (D=128)
__global__ __launch_bounds__(256) void ln_res(float* __restrict__ feat,
    const float* __restrict__ delta, const float* __restrict__ g,
    const float* __restrict__ b)
{
    int row = blockIdx.x * 4 + (threadIdx.x >> 6);
    int lane = threadIdx.x & 63;
    const size_t base = (size_t)row * 128 + lane * 2;
    float2 f  = *reinterpret_cast<const float2*>(feat + base);
    float2 dd = *reinterpret_cast<const float2*>(delta + base);
    float x0 = f.x + dd.x, x1 = f.y + dd.y;
    float s = x0 + x1, ss = x0 * x0 + x1 * x1;
    #pragma unroll
    for (int off = 32; off; off >>= 1) { s += __shfl_xor(s, off); ss += __shfl_xor(ss, off); }
    float mu = s * 0.0078125f;
    float var = fmaxf(ss * 0.0078125f - mu * mu, 0.f);
    float inv = rsqrtf(var + 1e-5f);
    float2 gg = *reinterpret_cast<const float2*>(g + lane * 2);
    float2 bb = *reinterpret_cast<const float2*>(b + lane * 2);
    float2 r;
    r.x = (x0 - mu) * inv * gg.x + bb.x;
    r.y = (x1 - mu) * inv * gg.y + bb.y;
    *reinterpret_cast<float2*>(feat + base) = r;
}

// ------------------------------------------------------ BEV scatter (-> bf16)
__global__ __launch_bounds__(256) void scatter_kernel(const float* __restrict__ feat,
    const int* __restrict__ coors, unsigned short* __restrict__ canvas)
{
    int idx = blockIdx.x * 256 + threadIdx.x;
    if (idx >= NVOX * 16) return;
    int n = idx >> 4, c8 = (idx & 15) << 3;
    int b = coors[n * 4], y = coors[n * 4 + 2], x = coors[n * 4 + 3];
    const float* src = feat + (size_t)n * 128 + c8;
    float4 u0 = *reinterpret_cast<const float4*>(src);
    float4 u1 = *reinterpret_cast<const float4*>(src + 4);
    short8v v;
    v[0]=(short)f2bf(u0.x); v[1]=(short)f2bf(u0.y); v[2]=(short)f2bf(u0.z); v[3]=(short)f2bf(u0.w);
    v[4]=(short)f2bf(u1.x); v[5]=(short)f2bf(u1.y); v[6]=(short)f2bf(u1.z); v[7]=(short)f2bf(u1.w);
    size_t p = (((size_t)b * 400 + y) * 400 + x) * 128 + c8;
    *reinterpret_cast<short8v*>(canvas + p) = v;
}

// ------------------- conv weight re-layout -> bf16 [i][ky*3+kx][cout][cin]
__global__ __launch_bounds__(256) void wtrans_kernel(const float* __restrict__ cw,
                                                     unsigned short* __restrict__ wbuf)
{
    int idx = blockIdx.x * 256 + threadIdx.x;
    if (idx >= 2 * 9 * 128 * 128) return;
    int ci = idx & 127;
    int co = (idx >> 7) & 127;
    int kk = (idx >> 14) % 9;
    int i  = idx / (9 * 16384);
    wbuf[idx] = f2bf(cw[(((size_t)i * 128 + co) * 128 + ci) * 9 + kk]);
}

// ---------------- 3x3 dilated(2) conv + BN + ReLU, bf16 MFMA implicit GEMM
// in: NHWC bf16 (2,400,400,128). NCHW_OUT: fp32 NCHW out, else bf16 NHWC out.
template<bool NCHW_OUT>
__global__ __launch_bounds__(256) void conv_mfma(
    const unsigned short* __restrict__ in, const unsigned short* __restrict__ wbuf,
    const float* __restrict__ g, const float* __restrict__ bsh,
    const float* __restrict__ bm, const float* __restrict__ bv,
    void* __restrict__ out)
{
    __shared__ unsigned short As[3 * 68 * 128];
    const int tid = threadIdx.x;
    const int lane = tid & 63, wave = tid >> 6;
    const int wr = wave >> 1, wc = wave & 1;
    const int llo = lane & 15, lhi = lane >> 4;
    const int y = blockIdx.y, x0 = blockIdx.x * 64, b = blockIdx.z;

    // stage 3 input rows (68 px x 128 cin), XOR-swizzled by px&7
    for (int c = tid; c < 3 * 68 * 16; c += 256) {
        int row = c / (68 * 16);
        int rem = c % (68 * 16);
        int xi = rem >> 4, c16 = rem & 15;
        int yy = y + 2 * row - 2;
        int xx = x0 - 2 + xi;
        short8v v = {};
        if (yy >= 0 && yy < 400 && xx >= 0 && xx < 400)
            v = *reinterpret_cast<const short8v*>(in + (((size_t)b * 400 + yy) * 400 + xx) * 128 + c16 * 8);
        int addr = (row * 68 + xi) * 256 + ((c16 * 16) ^ ((xi & 7) << 4));
        *reinterpret_cast<short8v*>((char*)As + addr) = v;
    }
    __syncthreads();

    f32x4 acc[2][4] = {};
    #pragma unroll
    for (int ky = 0; ky < 3; ++ky) {
        #pragma unroll
        for (int kx = 0; kx < 3; ++kx) {
            const unsigned short* wt = wbuf + (size_t)(ky * 3 + kx) * 16384;
            #pragma unroll
            for (int kk = 0; kk < 4; ++kk) {
                int kb = kk * 64 + lhi * 16;
                short8v a0, a1, bfr[4];
                #pragma unroll
                for (int i = 0; i < 2; ++i) {
                    int px = wr * 32 + i * 16 + llo + 2 * kx;
                    short8v t = *reinterpret_cast<const short8v*>(
                        (const char*)As + (ky * 68 + px) * 256 + (kb ^ ((px & 7) << 4)));
                    if (i) a1 = t; else a0 = t;
                }
                #pragma unroll
                for (int j = 0; j < 4; ++j) {
                    int co = wc * 64 + j * 16 + llo;
                    bfr[j] = *reinterpret_cast<const short8v*>(wt + co * 128 + kk * 32 + lhi * 8);
                }
                #pragma unroll
                for (int j = 0; j < 4; ++j) {
                    acc[0][j] = __builtin_amdgcn_mfma_f32_16x16x32_bf16(a0, bfr[j], acc[0][j], 0, 0, 0);
                    acc[1][j] = __builtin_amdgcn_mfma_f32_16x16x32_bf16(a1, bfr[j], acc[1][j], 0, 0, 0);
                }
            }
        }
    }
    #pragma unroll
    for (int j = 0; j < 4; ++j) {
        int co = wc * 64 + j * 16 + llo;
        float scale = rsqrtf(bv[co] + 1e-3f) * g[co];
        float shift = bsh[co] - bm[co] * scale;
        #pragma unroll
        for (int i = 0; i < 2; ++i) {
            #pragma unroll
            for (int rg = 0; rg < 4; ++rg) {
                int px = x0 + wr * 32 + i * 16 + lhi * 4 + rg;
                if (px < 400) {
                    float v = fmaxf(acc[i][j][rg] * scale + shift, 0.f);
                    if (NCHW_OUT)
                        ((float*)out)[(((size_t)b * 128 + co) * 400 + y) * 400 + px] = v;
                    else
                        ((unsigned short*)out)[(((size_t)b * 400 + y) * 400 + px) * 128 + co] = f2bf(v);
                }
            }
        }
    }
}

// ---------------------------------------------------------------- launcher
extern "C" void kernel_launch(void* const* d_in, const int* in_sizes, int n_in,
                              void* d_out, int out_size, void* d_ws, size_t ws_size,
                              hipStream_t stream) {
    const float* voxel_feat = (const float*)d_in[0];
    const int*   coors      = (const int*)d_in[1];
    const float* ciw0       = (const float*)d_in[2];
    const float* ciw1       = (const float*)d_in[3];
    const int* vx[2][2] = {{(const int*)d_in[4], (const int*)d_in[6]},
                           {(const int*)d_in[8], (const int*)d_in[10]}};
    const float* ipw = (const float*)d_in[12];
    const float* ipb = (const float*)d_in[13];
    const float* ow  = (const float*)d_in[14];
    const float* obp = (const float*)d_in[15];
    const float* l1w = (const float*)d_in[16];
    const float* l1b = (const float*)d_in[17];
    const float* l2w = (const float*)d_in[18];
    const float* l2b = (const float*)d_in[19];
    const float* g1  = (const float*)d_in[20];
    const float* b1  = (const float*)d_in[21];
    const float* g2  = (const float*)d_in[22];
    const float* b2  = (const float*)d_in[23];
    const float* cw  = (const float*)d_in[24];
    const float* bng = (const float*)d_in[25];
    const float* bnb = (const float*)d_in[26];
    const float* bnm = (const float*)d_in[27];
    const float* bnv = (const float*)d_in[28];

    float* F     = (float*)d_ws;
    float* feat  = F;                       // [0, 7.68M)
    float* attnb = F + 7680000;             // [7.68M, 15.36M)
    float* obuf  = F + 15360000;            // [15.36M, 23.04M)
    float* hbuf  = F + 23040000;            // [23.04M, 38.4M)
    float* pos0  = F + 38400000;            // [38.4M, 46.08M)
    float* pos1  = F + 46080000;            // [46.08M, 53.76M)
    unsigned short* ipwb = (unsigned short*)(F + 53760000);   // 589824 bf16
    unsigned short* owb  = ipwb + 589824;                     // 196608
    unsigned short* l1wb = owb + 196608;                      // 393216
    unsigned short* l2wb = l1wb + 393216;                     // 393216
    unsigned short* cwb  = (unsigned short*)(F + 54546432);   // 294912 bf16
    unsigned short* canvasb  = (unsigned short*)(F + 7680000);   // post-layers [7.68M,28.16M)
    unsigned short* canvas2b = (unsigned short*)(F + 28160000);  // post-layers [28.16M,48.64M)
    float* qkv = (float*)d_out;             // 23.04M floats scratch during layers

    hipMemcpyAsync(feat, voxel_feat, (size_t)7680000 * 4, hipMemcpyDeviceToDevice, stream);
    pos_kernel<<<30000, 256, 0, stream>>>(ciw0, pos0);
    pos_kernel<<<30000, 256, 0, stream>>>(ciw1, pos1);
    cvt_bf16<<<(589824 + 255) / 256, 256, 0, stream>>>(ipw, ipwb, 589824);
    cvt_bf16<<<(196608 + 255) / 256, 256, 0, stream>>>(ow,  owb,  196608);
    cvt_bf16<<<(393216 + 255) / 256, 256, 0, stream>>>(l1w, l1wb, 393216);
    cvt_bf16<<<(393216 + 255) / 256, 256, 0, stream>>>(l2w, l2wb, 393216);
    wtrans_kernel<<<(2 * 9 * 16384 + 255) / 256, 256, 0, stream>>>(cw, cwb);

    for (int li = 0; li < 12; ++li) {
        int s = li & 1;
        const float* pos = s ? pos1 : pos0;
        gemm_mfma<128, false><<<dim3(469, 3), 256, 0, stream>>>(
            feat, pos, 2, ipwb + (size_t)li * 49152, ipb + li * 384, qkv, NVOX, 384);
        attn_kernel<25, 8><<<dim3(960, 1), 256, 0, stream>>>(qkv, vx[s][0], 24000, obuf);
        attn_kernel<100, 4><<<dim3(360, 2), 256, 0, stream>>>(qkv, vx[s][1], 36000, obuf);
        gemm_mfma<128, false><<<dim3(469, 1), 256, 0, stream>>>(
            obuf, nullptr, 0, owb + (size_t)li * 16384, obp + li * 128, attnb, NVOX, 128);
        ln_res<<<15000, 256, 0, stream>>>(feat, attnb, g1 + li * 128, b1 + li * 128);
        gemm_mfma<128, true><<<dim3(469, 2), 256, 0, stream>>>(
            feat, nullptr, 0, l1wb + (size_t)li * 32768, l1b + li * 256, hbuf, NVOX, 256);
        gemm_mfma<256, false><<<dim3(469, 1), 256, 0, stream>>>(
            hbuf, nullptr, 0, l2wb + (size_t)li * 32768, l2b + li * 128, attnb, NVOX, 128);
        ln_res<<<15000, 256, 0, stream>>>(feat, attnb, g2 + li * 128, b2 + li * 128);
    }

    // BEV: zero bf16 canvas, scatter, conv1 (bf16 NHWC), conv2 (fp32 NCHW -> d_out)
    hipMemsetAsync(canvasb, 0, (size_t)40960000 * 2, stream);
    scatter_kernel<<<(NVOX * 16 + 255) / 256, 256, 0, stream>>>(feat, coors, canvasb);
    conv_mfma<false><<<dim3(7, 400, 2), 256, 0, stream>>>(
        canvasb, cwb, bng, bnb, bnm, bnv, canvas2b);
    conv_mfma<true><<<dim3(7, 400, 2), 256, 0, stream>>>(
        canvas2b, cwb + 9 * 16384, bng + 128, bnb + 128, bnm + 128, bnv + 128, (float*)d_out);
}

// Round 3
// 3292.130 us; speedup vs baseline: 2.8689x; 1.2132x over previous
//
#include <hip/hip_runtime.h>
#include <math.h>

#define NVOX 60000

typedef __attribute__((ext_vector_type(8))) short short8v;            // 8 bf16 raw
typedef __attribute__((ext_vector_type(8))) unsigned short ushort8v;  // 8 bf16 raw
typedef __attribute__((ext_vector_type(4))) float f32x4;

static __device__ __forceinline__ unsigned short f2bf(float f) {
    unsigned u = __float_as_uint(f);
    unsigned r = (u + 0x7fffu + ((u >> 16) & 1u)) >> 16;
    return (unsigned short)r;
}
static __device__ __forceinline__ float bf2f(unsigned short h) {
    return __uint_as_float(((unsigned)h) << 16);
}

// ---------------------------------------------------------------- pos embed (bf16 out)
__global__ __launch_bounds__(256) void pos_kernel(const float* __restrict__ ciw,
                                                  unsigned short* __restrict__ pos) {
    int idx = blockIdx.x * 256 + threadIdx.x;
    if (idx >= NVOX * 128) return;
    int n = idx >> 7, d = idx & 127;
    int c = d >> 6, t = (d & 63) >> 1;
    float xy = ciw[n * 2 + c] - 6.0f;
    float inv = exp2f((float)t * (13.287712379549449f / 32.0f)); // 10000^(t/32)
    float e = xy / inv;
    pos[idx] = f2bf((d & 1) ? cosf(e) : sinf(e));
}

// ------------------------------------------------------- fp32 -> bf16 convert
__global__ __launch_bounds__(256) void cvt_bf16(const float* __restrict__ in,
                                                unsigned short* __restrict__ out, int n) {
    int idx = blockIdx.x * 256 + threadIdx.x;
    if (idx < n) out[idx] = f2bf(in[idx]);
}

// ----------------------------------------- MFMA GEMM: C = A*W^T + b (+variants)
// A: f32 (optionally + bf16 Aadd for col-blocks < add_nblk) or bf16.
// C: f32 / bf16, optional GELU.  LNF: fused residual+LayerNorm epilogue
// (requires N==128, gridDim.y==1): feat = LN(feat + A@W^T + b) * g + b2.
template<int KTOT, bool ABF16, bool ADD, bool GELU, bool CBF16, bool LNF>
__global__ __launch_bounds__(256) void gemm_mfma(
    const void* __restrict__ Ap, const unsigned short* __restrict__ Aadd, int add_nblk,
    const unsigned short* __restrict__ W, const float* __restrict__ bias,
    void* __restrict__ Cp, int M, int ldc,
    float* __restrict__ feat, const float* __restrict__ lng, const float* __restrict__ lnb)
{
    __shared__ unsigned short As[128 * 64];
    __shared__ unsigned short Ws[128 * 64];
    __shared__ float2 lnsum[128][2];
    const int tid = threadIdx.x;
    const int lane = tid & 63, wave = tid >> 6;
    const int wr = wave >> 1, wc = wave & 1;
    const int llo = lane & 15, lhi = lane >> 4;
    const int m0 = blockIdx.x * 128;
    const int n0 = blockIdx.y * 128;
    const bool addp = ADD && ((int)blockIdx.y < add_nblk);
    f32x4 acc[4][4] = {};

    for (int k0 = 0; k0 < KTOT; k0 += 64) {
        #pragma unroll
        for (int p = 0; p < 4; ++p) {
            int c = tid + p * 256;          // 16B chunk id, 1024 total
            int r = c >> 3, c16 = c & 7;
            int addr = r * 128 + ((c16 * 16) ^ ((r & 7) << 4));
            int m = m0 + r;
            short8v av = {};
            if (m < M) {
                if (ABF16) {
                    av = *reinterpret_cast<const short8v*>(
                        (const unsigned short*)Ap + (size_t)m * KTOT + k0 + c16 * 8);
                } else {
                    const float* src = (const float*)Ap + (size_t)m * KTOT + k0 + c16 * 8;
                    float4 u0 = *reinterpret_cast<const float4*>(src);
                    float4 u1 = *reinterpret_cast<const float4*>(src + 4);
                    float vv[8] = {u0.x,u0.y,u0.z,u0.w,u1.x,u1.y,u1.z,u1.w};
                    if (ADD && addp) {
                        ushort8v pu = *reinterpret_cast<const ushort8v*>(
                            Aadd + (size_t)m * 128 + k0 + c16 * 8);
                        #pragma unroll
                        for (int q = 0; q < 8; ++q) vv[q] += bf2f(pu[q]);
                    }
                    #pragma unroll
                    for (int q = 0; q < 8; ++q) av[q] = (short)f2bf(vv[q]);
                }
            }
            *reinterpret_cast<short8v*>((char*)As + addr) = av;
            *reinterpret_cast<short8v*>((char*)Ws + addr) =
                *reinterpret_cast<const short8v*>(W + (size_t)(n0 + r) * KTOT + k0 + c16 * 8);
        }
        __syncthreads();
        #pragma unroll
        for (int kk = 0; kk < 2; ++kk) {
            int kb = kk * 64 + lhi * 16;
            short8v af[4], bf[4];
            #pragma unroll
            for (int i = 0; i < 4; ++i) {
                int r = wr * 64 + i * 16 + llo;
                af[i] = *reinterpret_cast<const short8v*>((const char*)As + r * 128 + (kb ^ ((r & 7) << 4)));
                int cc = wc * 64 + i * 16 + llo;
                bf[i] = *reinterpret_cast<const short8v*>((const char*)Ws + cc * 128 + (kb ^ ((cc & 7) << 4)));
            }
            #pragma unroll
            for (int i = 0; i < 4; ++i)
                #pragma unroll
                for (int j = 0; j < 4; ++j)
                    acc[i][j] = __builtin_amdgcn_mfma_f32_16x16x32_bf16(af[i], bf[j], acc[i][j], 0, 0, 0);
        }
        __syncthreads();
    }

    if (LNF) {
        // residual + LayerNorm over the 128 cols held by this block
        float s1[4][4] = {}, s2[4][4] = {};
        #pragma unroll
        for (int i = 0; i < 4; ++i)
            #pragma unroll
            for (int rg = 0; rg < 4; ++rg) {
                int m = m0 + wr * 64 + i * 16 + lhi * 4 + rg;
                if (m < M) {
                    #pragma unroll
                    for (int j = 0; j < 4; ++j) {
                        int n = wc * 64 + j * 16 + llo;
                        float x = feat[(size_t)m * 128 + n] + acc[i][j][rg] + bias[n];
                        s1[i][rg] += x; s2[i][rg] += x * x;
                    }
                }
            }
        #pragma unroll
        for (int i = 0; i < 4; ++i)
            #pragma unroll
            for (int rg = 0; rg < 4; ++rg) {
                #pragma unroll
                for (int off = 1; off < 16; off <<= 1) {
                    s1[i][rg] += __shfl_xor(s1[i][rg], off);
                    s2[i][rg] += __shfl_xor(s2[i][rg], off);
                }
                if (llo == 0)
                    lnsum[wr * 64 + i * 16 + lhi * 4 + rg][wc] = make_float2(s1[i][rg], s2[i][rg]);
            }
        __syncthreads();
        #pragma unroll
        for (int i = 0; i < 4; ++i)
            #pragma unroll
            for (int rg = 0; rg < 4; ++rg) {
                int r = wr * 64 + i * 16 + lhi * 4 + rg;
                int m = m0 + r;
                if (m >= M) continue;
                float2 a0 = lnsum[r][0], a1 = lnsum[r][1];
                float mu = (a0.x + a1.x) * 0.0078125f;
                float var = fmaxf((a0.y + a1.y) * 0.0078125f - mu * mu, 0.f);
                float inv = rsqrtf(var + 1e-5f);
                #pragma unroll
                for (int j = 0; j < 4; ++j) {
                    int n = wc * 64 + j * 16 + llo;
                    float x = feat[(size_t)m * 128 + n] + acc[i][j][rg] + bias[n];
                    feat[(size_t)m * 128 + n] = (x - mu) * inv * lng[n] + lnb[n];
                }
            }
    } else {
        #pragma unroll
        for (int j = 0; j < 4; ++j) {
            int n = n0 + wc * 64 + j * 16 + llo;
            float bn = bias[n];
            #pragma unroll
            for (int i = 0; i < 4; ++i) {
                #pragma unroll
                for (int rg = 0; rg < 4; ++rg) {
                    int m = m0 + wr * 64 + i * 16 + lhi * 4 + rg;
                    if (m < M) {
                        float v = acc[i][j][rg] + bn;
                        if (GELU) v = 0.5f * v * (1.0f + erff(v * 0.7071067811865475f));
                        if (CBF16) ((unsigned short*)Cp)[(size_t)m * ldc + n] = f2bf(v);
                        else       ((float*)Cp)[(size_t)m * ldc + n] = v;
                    }
                }
            }
        }
    }
}

// ------------------------------------------------------- windowed attention (bf16 qkv)
template<int CAPT, int HG>
__global__ __launch_bounds__(256) void attn_kernel(
    const unsigned short* __restrict__ qkv, const int* __restrict__ vlist, int nvox,
    unsigned short* __restrict__ oout)
{
    __shared__ float Ks[CAPT][HG * 16];
    __shared__ float Vs[CAPT][HG * 16];
    __shared__ int vl[CAPT];
    const int w = blockIdx.x;
    const int hb = blockIdx.y * HG;
    const int tid = threadIdx.x;
    const int T = min(CAPT, nvox - w * CAPT);
    if (tid < T) vl[tid] = vlist[w * CAPT + tid];
    constexpr int R8 = HG * 2;   // 8-elem chunks per row
    for (int idx = tid; idx < T * R8; idx += 256) {
        int t = idx / R8, c8 = (idx % R8) * 8;
        int vox = vlist[w * CAPT + t];
        const unsigned short* base = qkv + (size_t)vox * 384 + hb * 16 + c8;
        ushort8v kv = *reinterpret_cast<const ushort8v*>(base + 128);
        ushort8v vv = *reinterpret_cast<const ushort8v*>(base + 256);
        #pragma unroll
        for (int q = 0; q < 8; ++q) { Ks[t][c8 + q] = bf2f(kv[q]); Vs[t][c8 + q] = bf2f(vv[q]); }
    }
    __syncthreads();
    const int ITEMS = T * HG;
    for (int item = tid; item < ITEMS; item += 256) {
        int h = item & (HG - 1);
        int q = item / HG;
        int vq = vl[q];
        const unsigned short* qb = qkv + (size_t)vq * 384 + (hb + h) * 16;
        ushort8v qa = *reinterpret_cast<const ushort8v*>(qb);
        ushort8v qc = *reinterpret_cast<const ushort8v*>(qb + 8);
        float4 q0 = make_float4(bf2f(qa[0]), bf2f(qa[1]), bf2f(qa[2]), bf2f(qa[3]));
        float4 q1 = make_float4(bf2f(qa[4]), bf2f(qa[5]), bf2f(qa[6]), bf2f(qa[7]));
        float4 q2 = make_float4(bf2f(qc[0]), bf2f(qc[1]), bf2f(qc[2]), bf2f(qc[3]));
        float4 q3 = make_float4(bf2f(qc[4]), bf2f(qc[5]), bf2f(qc[6]), bf2f(qc[7]));
        float mx = -INFINITY, l = 0.f;
        float4 o0 = make_float4(0,0,0,0), o1 = o0, o2 = o0, o3 = o0;
        for (int t = 0; t < T; ++t) {
            const float4* kr = reinterpret_cast<const float4*>(&Ks[t][h * 16]);
            float4 k0 = kr[0], k1 = kr[1], k2 = kr[2], k3 = kr[3];
            float s = q0.x*k0.x + q0.y*k0.y + q0.z*k0.z + q0.w*k0.w
                    + q1.x*k1.x + q1.y*k1.y + q1.z*k1.z + q1.w*k1.w
                    + q2.x*k2.x + q2.y*k2.y + q2.z*k2.z + q2.w*k2.w
                    + q3.x*k3.x + q3.y*k3.y + q3.z*k3.z + q3.w*k3.w;
            s *= 0.25f;
            float mo = mx;
            mx = fmaxf(mx, s);
            float cc = __expf(mo - mx);
            float p  = __expf(s - mx);
            l = l * cc + p;
            const float4* vr = reinterpret_cast<const float4*>(&Vs[t][h * 16]);
            float4 v0 = vr[0], v1 = vr[1], v2 = vr[2], v3 = vr[3];
            o0.x = o0.x*cc + p*v0.x; o0.y = o0.y*cc + p*v0.y; o0.z = o0.z*cc + p*v0.z; o0.w = o0.w*cc + p*v0.w;
            o1.x = o1.x*cc + p*v1.x; o1.y = o1.y*cc + p*v1.y; o1.z = o1.z*cc + p*v1.z; o1.w = o1.w*cc + p*v1.w;
            o2.x = o2.x*cc + p*v2.x; o2.y = o2.y*cc + p*v2.y; o2.z = o2.z*cc + p*v2.z; o2.w = o2.w*cc + p*v2.w;
            o3.x = o3.x*cc + p*v3.x; o3.y = o3.y*cc + p*v3.y; o3.z = o3.z*cc + p*v3.z; o3.w = o3.w*cc + p*v3.w;
        }
        float rl = 1.0f / l;
        ushort8v r0, r1;
        r0[0]=f2bf(o0.x*rl); r0[1]=f2bf(o0.y*rl); r0[2]=f2bf(o0.z*rl); r0[3]=f2bf(o0.w*rl);
        r0[4]=f2bf(o1.x*rl); r0[5]=f2bf(o1.y*rl); r0[6]=f2bf(o1.z*rl); r0[7]=f2bf(o1.w*rl);
        r1[0]=f2bf(o2.x*rl); r1[1]=f2bf(o2.y*rl); r1[2]=f2bf(o2.z*rl); r1[3]=f2bf(o2.w*rl);
        r1[4]=f2bf(o3.x*rl); r1[5]=f2bf(o3.y*rl); r1[6]=f2bf(o3.z*rl); r1[7]=f2bf(o3.w*rl);
        unsigned short* op = oout + (size_t)vq * 128 + (hb + h) * 16;
        *reinterpret_cast<ushort8v*>(op) = r0;
        *reinterpret_cast<ushort8v*>(op + 8) = r1;
    }
}

// ------------------------------------------------------ BEV scatter (f32 feat -> bf16)
__global__ __launch_bounds__(256) void scatter_kernel(const float* __restrict__ feat,
    const int* __restrict__ coors, unsigned short* __restrict__ canvas)
{
    int idx = blockIdx.x * 256 + threadIdx.x;
    if (idx >= NVOX * 16) return;
    int n = idx >> 4, c8 = (idx & 15) << 3;
    int b = coors[n * 4], y = coors[n * 4 + 2], x = coors[n * 4 + 3];
    const float* src = feat + (size_t)n * 128 + c8;
    float4 u0 = *reinterpret_cast<const float4*>(src);
    float4 u1 = *reinterpret_cast<const float4*>(src + 4);
    ushort8v v;
    v[0]=f2bf(u0.x); v[1]=f2bf(u0.y); v[2]=f2bf(u0.z); v[3]=f2bf(u0.w);
    v[4]=f2bf(u1.x); v[5]=f2bf(u1.y); v[6]=f2bf(u1.z); v[7]=f2bf(u1.w);
    size_t p = (((size_t)b * 400 + y) * 400 + x) * 128 + c8;
    *reinterpret_cast<ushort8v*>(canvas + p) = v;
}

// ------------------- conv weight re-layout -> bf16 [i][ky*3+kx][cout][cin]
__global__ __launch_bounds__(256) void wtrans_kernel(const float* __restrict__ cw,
                                                     unsigned short* __restrict__ wbuf)
{
    int idx = blockIdx.x * 256 + threadIdx.x;
    if (idx >= 2 * 9 * 128 * 128) return;
    int ci = idx & 127;
    int co = (idx >> 7) & 127;
    int kk = (idx >> 14) % 9;
    int i  = idx / (9 * 16384);
    wbuf[idx] = f2bf(cw[(((size_t)i * 128 + co) * 128 + ci) * 9 + kk]);
}

// ---------------- 3x3 dilated(2) conv + BN + ReLU, bf16 MFMA implicit GEMM
// Block: 64px(x) x 128cout x 4y.  512 thr = 8 waves (2px x 2co x 2yg).
// Stages 8 input rows once (139 KB LDS).  in: NHWC bf16 (2,400,400,128).
template<bool NCHW_OUT>
__global__ __launch_bounds__(512) void conv_mfma(
    const unsigned short* __restrict__ in, const unsigned short* __restrict__ wbuf,
    const float* __restrict__ g, const float* __restrict__ bsh,
    const float* __restrict__ bm, const float* __restrict__ bv,
    void* __restrict__ out)
{
    __shared__ unsigned short As[8 * 68 * 128];   // 139264 B
    const int tid = threadIdx.x;
    const int lane = tid & 63, wave = tid >> 6;
    const int pxg = wave & 1, cog = (wave >> 1) & 1, yg = wave >> 2;
    const int llo = lane & 15, lhi = lane >> 4;
    const int x0 = blockIdx.x * 64, y0 = blockIdx.y * 4, b = blockIdx.z;

    for (int c = tid; c < 8 * 68 * 16; c += 512) {
        int row = c / (68 * 16);
        int rem = c % (68 * 16);
        int xi = rem >> 4, c16 = rem & 15;
        int yy = y0 - 2 + row, xx = x0 - 2 + xi;
        short8v v = {};
        if (yy >= 0 && yy < 400 && xx >= 0 && xx < 400)
            v = *reinterpret_cast<const short8v*>(in + (((size_t)b * 400 + yy) * 400 + xx) * 128 + c16 * 8);
        int addr = (row * 68 + xi) * 256 + ((c16 * 16) ^ ((xi & 7) << 4));
        *reinterpret_cast<short8v*>((char*)As + addr) = v;
    }
    __syncthreads();

    f32x4 acc[2][2][4] = {};    // [dy][i(px)][j(co)]
    #pragma unroll
    for (int ky = 0; ky < 3; ++ky) {
        #pragma unroll
        for (int kx = 0; kx < 3; ++kx) {
            const unsigned short* wt = wbuf + (size_t)(ky * 3 + kx) * 16384 + (size_t)cog * 64 * 128;
            #pragma unroll
            for (int kk = 0; kk < 4; ++kk) {
                short8v bfr[4];
                #pragma unroll
                for (int j = 0; j < 4; ++j)
                    bfr[j] = *reinterpret_cast<const short8v*>(wt + (j * 16 + llo) * 128 + kk * 32 + lhi * 8);
                short8v a[2][2];
                #pragma unroll
                for (int dy = 0; dy < 2; ++dy)
                    #pragma unroll
                    for (int i = 0; i < 2; ++i) {
                        int px = pxg * 32 + i * 16 + llo + 2 * kx;
                        int row = yg * 2 + dy + 2 * ky;
                        a[dy][i] = *reinterpret_cast<const short8v*>(
                            (const char*)As + (row * 68 + px) * 256 + ((kk * 64 + lhi * 16) ^ ((px & 7) << 4)));
                    }
                #pragma unroll
                for (int dy = 0; dy < 2; ++dy)
                    #pragma unroll
                    for (int i = 0; i < 2; ++i)
                        #pragma unroll
                        for (int j = 0; j < 4; ++j)
                            acc[dy][i][j] = __builtin_amdgcn_mfma_f32_16x16x32_bf16(
                                a[dy][i], bfr[j], acc[dy][i][j], 0, 0, 0);
            }
        }
    }
    #pragma unroll
    for (int j = 0; j < 4; ++j) {
        int co = cog * 64 + j * 16 + llo;
        float scale = rsqrtf(bv[co] + 1e-3f) * g[co];
        float shift = bsh[co] - bm[co] * scale;
        #pragma unroll
        for (int dy = 0; dy < 2; ++dy) {
            int y = y0 + yg * 2 + dy;
            #pragma unroll
            for (int i = 0; i < 2; ++i) {
                #pragma unroll
                for (int rg = 0; rg < 4; ++rg) {
                    int px = x0 + pxg * 32 + i * 16 + lhi * 4 + rg;
                    if (px < 400) {
                        float v = fmaxf(acc[dy][i][j][rg] * scale + shift, 0.f);
                        if (NCHW_OUT)
                            ((float*)out)[(((size_t)b * 128 + co) * 400 + y) * 400 + px] = v;
                        else
                            ((unsigned short*)out)[(((size_t)b * 400 + y) * 400 + px) * 128 + co] = f2bf(v);
                    }
                }
            }
        }
    }
}

// ---------------------------------------------------------------- launcher
extern "C" void kernel_launch(void* const* d_in, const int* in_sizes, int n_in,
                              void* d_out, int out_size, void* d_ws, size_t ws_size,
                              hipStream_t stream) {
    const float* voxel_feat = (const float*)d_in[0];
    const int*   coors      = (const int*)d_in[1];
    const float* ciw0       = (const float*)d_in[2];
    const float* ciw1       = (const float*)d_in[3];
    const int* vx[2][2] = {{(const int*)d_in[4], (const int*)d_in[6]},
                           {(const int*)d_in[8], (const int*)d_in[10]}};
    const float* ipw = (const float*)d_in[12];
    const float* ipb = (const float*)d_in[13];
    const float* ow  = (const float*)d_in[14];
    const float* obp = (const float*)d_in[15];
    const float* l1w = (const float*)d_in[16];
    const float* l1b = (const float*)d_in[17];
    const float* l2w = (const float*)d_in[18];
    const float* l2b = (const float*)d_in[19];
    const float* g1  = (const float*)d_in[20];
    const float* b1  = (const float*)d_in[21];
    const float* g2  = (const float*)d_in[22];
    const float* b2  = (const float*)d_in[23];
    const float* cw  = (const float*)d_in[24];
    const float* bng = (const float*)d_in[25];
    const float* bnb = (const float*)d_in[26];
    const float* bnm = (const float*)d_in[27];
    const float* bnv = (const float*)d_in[28];

    float* F = (float*)d_ws;
    // weights (bf16) at front, then feat f32, then bf16 activations.
    unsigned short* W0   = (unsigned short*)F;           // 1,867,776 ushorts
    unsigned short* ipwb = W0;                           // 589824
    unsigned short* owb  = W0 + 589824;                  // 196608
    unsigned short* l1wb = W0 + 786432;                  // 393216
    unsigned short* l2wb = W0 + 1179648;                 // 393216
    unsigned short* cwb  = W0 + 1572864;                 // 294912
    float* feat = F + 940000;                            // 7.68M f32
    unsigned short* pos0  = (unsigned short*)(F + 8620000);   // 7.68M bf16
    unsigned short* pos1  = (unsigned short*)(F + 12460000);  // 7.68M bf16
    unsigned short* obufb = (unsigned short*)(F + 16300000);  // 7.68M bf16
    unsigned short* hbufb = (unsigned short*)(F + 20140000);  // 15.36M bf16
    // conv phase (layer buffers dead; feat still live for scatter):
    unsigned short* canvasb  = (unsigned short*)(F + 8620000);   // 40.96M bf16
    unsigned short* canvas2b = (unsigned short*)(F + 29100000);  // 40.96M bf16
    unsigned short* qkvb = (unsigned short*)d_out;       // 23.04M bf16 scratch

    hipMemcpyAsync(feat, voxel_feat, (size_t)7680000 * 4, hipMemcpyDeviceToDevice, stream);
    pos_kernel<<<30000, 256, 0, stream>>>(ciw0, pos0);
    pos_kernel<<<30000, 256, 0, stream>>>(ciw1, pos1);
    cvt_bf16<<<(589824 + 255) / 256, 256, 0, stream>>>(ipw, ipwb, 589824);
    cvt_bf16<<<(196608 + 255) / 256, 256, 0, stream>>>(ow,  owb,  196608);
    cvt_bf16<<<(393216 + 255) / 256, 256, 0, stream>>>(l1w, l1wb, 393216);
    cvt_bf16<<<(393216 + 255) / 256, 256, 0, stream>>>(l2w, l2wb, 393216);
    wtrans_kernel<<<(2 * 9 * 16384 + 255) / 256, 256, 0, stream>>>(cw, cwb);

    for (int li = 0; li < 12; ++li) {
        int s = li & 1;
        const unsigned short* pos = s ? pos1 : pos0;
        // QKV: q,k get +pos; bf16 out into d_out scratch
        gemm_mfma<128, false, true, false, true, false><<<dim3(469, 3), 256, 0, stream>>>(
            feat, pos, 2, ipwb + (size_t)li * 49152, ipb + li * 384, qkvb, NVOX, 384,
            nullptr, nullptr, nullptr);
        attn_kernel<25, 8><<<dim3(960, 1), 256, 0, stream>>>(qkvb, vx[s][0], 24000, obufb);
        attn_kernel<100, 4><<<dim3(360, 2), 256, 0, stream>>>(qkvb, vx[s][1], 36000, obufb);
        // out-proj + residual + LN1 fused
        gemm_mfma<128, true, false, false, false, true><<<dim3(469, 1), 256, 0, stream>>>(
            obufb, nullptr, 0, owb + (size_t)li * 16384, obp + li * 128, nullptr, NVOX, 128,
            feat, g1 + li * 128, b1 + li * 128);
        // FFN1 + GELU, bf16 out
        gemm_mfma<128, false, false, true, true, false><<<dim3(469, 2), 256, 0, stream>>>(
            feat, nullptr, 0, l1wb + (size_t)li * 32768, l1b + li * 256, hbufb, NVOX, 256,
            nullptr, nullptr, nullptr);
        // FFN2 + residual + LN2 fused
        gemm_mfma<256, true, false, false, false, true><<<dim3(469, 1), 256, 0, stream>>>(
            hbufb, nullptr, 0, l2wb + (size_t)li * 32768, l2b + li * 128, nullptr, NVOX, 128,
            feat, g2 + li * 128, b2 + li * 128);
    }

    // BEV: zero bf16 canvas, scatter, conv1 (bf16 NHWC), conv2 (fp32 NCHW -> d_out)
    hipMemsetAsync(canvasb, 0, (size_t)40960000 * 2, stream);
    scatter_kernel<<<(NVOX * 16 + 255) / 256, 256, 0, stream>>>(feat, coors, canvasb);
    conv_mfma<false><<<dim3(7, 100, 2), 512, 0, stream>>>(
        canvasb, cwb, bng, bnb, bnm, bnv, canvas2b);
    conv_mfma<true><<<dim3(7, 100, 2), 512, 0, stream>>>(
        canvas2b, cwb + 9 * 16384, bng + 128, bnb + 128, bnm + 128, bnv + 128, (float*)d_out);
}